// Round 1
// 423.412 us; speedup vs baseline: 1.0094x; 1.0094x over previous
//
#include <hip/hip_runtime.h>

#define HIDDEN 1024
#define INTER  704
#define NEXP   32
#define TM     128

typedef __attribute__((ext_vector_type(8))) short bf16x8;
typedef __attribute__((ext_vector_type(4))) float f32x4;

__device__ __forceinline__ unsigned short f2bf(float f) {
    union { float f; unsigned u; } v; v.f = f;
    unsigned r = v.u + 0x7FFF + ((v.u >> 16) & 1);   // RNE
    return (unsigned short)(r >> 16);
}
__device__ __forceinline__ unsigned pkbf(float lo, float hi) {
    return (unsigned)f2bf(lo) | ((unsigned)f2bf(hi) << 16);
}
__device__ __forceinline__ float fcomp(const float4& v, int c) {
    return c == 0 ? v.x : c == 1 ? v.y : c == 2 ? v.z : v.w;
}

__device__ __forceinline__ void load_lds16(const void* g, void* l) {
    __builtin_amdgcn_global_load_lds(
        (const __attribute__((address_space(1))) void*)g,
        (__attribute__((address_space(3))) void*)l, 16, 0, 0);
}

// map block m-index -> (expert, global row0, valid rows) over ragged groups
__device__ __forceinline__ bool map_tile(const int* s_tpe, int bm,
                                         int& row0, int& rows, int& e) {
    int start = 0, rem = bm;
    for (int i = 0; i < NEXP; ++i) {
        int g = s_tpe[i];
        int nt = (g + TM - 1) / TM;
        if (rem < nt) { row0 = start + rem * TM; rows = min(TM, g - rem * TM); e = i; return true; }
        rem -= nt; start += g;
    }
    return false;
}

// ---------------- prep: x fp32 -> bf16 (same layout) ----------------
__global__ void cvt_x(const float* __restrict__ x, unsigned short* __restrict__ xb, int n4) {
    int i = blockIdx.x * blockDim.x + threadIdx.x;
    for (; i < n4; i += gridDim.x * blockDim.x) {
        float4 v = ((const float4*)x)[i];
        uint2 o;
        o.x = pkbf(v.x, v.y);
        o.y = pkbf(v.z, v.w);
        ((uint2*)xb)[i] = o;
    }
}

// ---------------- GEMM1 + SwiGLU: h = silu(x@w1) * (x@w3) ----------------
// Pipelined: A via global_load_lds 2 chunks deep (3-slot LDS ring),
// B via regs 2 chunks deep (bv0/bv1 ping-pong), raw s_barrier with
// counted vmcnt(6) so next-chunk loads stay in flight across barriers.
__global__ __launch_bounds__(256, 3)
void gemm1_swiglu(const unsigned short* __restrict__ xb, const int* __restrict__ tpe,
                  const float* __restrict__ w1w3, unsigned short* __restrict__ h)
{
    __shared__ int s_tpe[NEXP];
    __shared__ __align__(16) unsigned short sA[3][128 * 32];  // ring: chunk x -> slot x%3
    __shared__ __align__(16) unsigned short sB[2][128 * 32];  // ping-pong

    int t = threadIdx.x;
    if (t < NEXP) s_tpe[t] = tpe[t];
    __syncthreads();

    int row0, rows, e;
    if (!map_tile(s_tpe, blockIdx.x, row0, rows, e)) return;
    int jb = blockIdx.y;   // 0..10

    int wv = t >> 6, lane = t & 63, l16 = lane & 15, quad = lane >> 4;
    int wr = wv >> 1, wc = wv & 1;

    int srow = lane >> 2, sblk = lane & 3;
    int gblk = sblk ^ (srow & 3);
    int bs = t & 1, bg = (t >> 1) & 7, kq = t >> 4;   // kq 0..15
    int xk = l16 & 3;

    const unsigned short* abase = xb + (size_t)row0 * HIDDEN;
    const float* bbase = w1w3 + (size_t)e * HIDDEN * 1408 + bs * 704 + jb * 64 + bg * 8;

    f32x4 acc[4][4];
    #pragma unroll
    for (int i = 0; i < 4; i++)
        #pragma unroll
        for (int j = 0; j < 4; j++) acc[i][j] = (f32x4)(0.f);

    auto loadB = [&](int ko, float4 (&bv)[4]) {
        const float* p = bbase + (size_t)(ko + 2 * kq) * 1408;
        bv[0] = *(const float4*)(p);
        bv[1] = *(const float4*)(p + 4);
        bv[2] = *(const float4*)(p + 1408);
        bv[3] = *(const float4*)(p + 1408 + 4);
    };
    auto stageA = [&](unsigned short* dst, int ko) {
        #pragma unroll
        for (int i = 0; i < 2; ++i) {
            int r = wv * 32 + i * 16 + srow;
            if (r < rows)
                load_lds16(abase + (size_t)r * HIDDEN + ko + gblk * 8,
                           dst + (wv * 32 + i * 16) * 32);
        }
    };
    auto writeB = [&](unsigned short* dst, const float4 (&bv)[4]) {
        #pragma unroll
        for (int j = 0; j < 8; ++j) {
            float lo = (j < 4) ? fcomp(bv[0], j) : fcomp(bv[1], j - 4);
            float hi = (j < 4) ? fcomp(bv[2], j) : fcomp(bv[3], j - 4);
            int c = 16 * bg + 2 * j + bs;
            int key = (c >> 3) & 3;
            int idx = c * 32 + (((kq >> 2) ^ key) << 3) + ((kq & 3) << 1);
            *(unsigned*)&dst[idx] = pkbf(lo, hi);
        }
    };
    auto compute = [&](const unsigned short* A, const unsigned short* B) {
        bf16x8 a[4], b[4];
        #pragma unroll
        for (int i = 0; i < 4; ++i) {
            a[i] = *(const bf16x8*)&A[(wr * 64 + i * 16 + l16) * 32 + ((quad ^ xk) << 3)];
            int c = wc * 64 + i * 16 + l16;
            b[i] = *(const bf16x8*)&B[c * 32 + ((quad ^ ((c >> 3) & 3)) << 3)];
        }
        #pragma unroll
        for (int rt = 0; rt < 4; ++rt)
            #pragma unroll
            for (int ct = 0; ct < 4; ++ct)
                acc[rt][ct] = __builtin_amdgcn_mfma_f32_16x16x32_bf16(a[rt], b[ct], acc[rt][ct], 0, 0, 0);
    };

    const int NK = HIDDEN / 32;   // 32 chunks
    float4 bv0[4], bv1[4];

    // prologue: chunk0 -> sA[0]+sB[0]; chunk1 -> sA[1] (DMA) + bv1 (regs)
    stageA(&sA[0][0], 0);
    asm volatile("" ::: "memory");
    loadB(0, bv0);
    asm volatile("" ::: "memory");
    stageA(&sA[1][0], 32);
    asm volatile("" ::: "memory");
    loadB(32, bv1);
    writeB(&sB[0][0], bv0);
    asm volatile("s_waitcnt vmcnt(6) lgkmcnt(0)" ::: "memory");
    __builtin_amdgcn_s_barrier();

    int rd = 0, bufB = 0;
    // bodies b = 1 .. NK-2 (NK-2 = 30, even): body b computes chunk b-1
    for (int b = 1; b <= NK - 2; b += 2) {
        // body b (odd): cur = bv1, prefetch into bv0
        int st = rd + 2; if (st >= 3) st -= 3;
        stageA(&sA[st][0], (b + 1) * 32);
        asm volatile("" ::: "memory");
        loadB((b + 1) * 32, bv0);
        compute(&sA[rd][0], &sB[bufB][0]);
        writeB(&sB[bufB ^ 1][0], bv1);
        asm volatile("s_waitcnt vmcnt(6) lgkmcnt(0)" ::: "memory");
        __builtin_amdgcn_s_barrier();
        rd = rd + 1; if (rd >= 3) rd -= 3;
        bufB ^= 1;
        // body b+1 (even): cur = bv0, prefetch into bv1
        st = rd + 2; if (st >= 3) st -= 3;
        stageA(&sA[st][0], (b + 2) * 32);
        asm volatile("" ::: "memory");
        loadB((b + 2) * 32, bv1);
        compute(&sA[rd][0], &sB[bufB][0]);
        writeB(&sB[bufB ^ 1][0], bv0);
        asm volatile("s_waitcnt vmcnt(6) lgkmcnt(0)" ::: "memory");
        __builtin_amdgcn_s_barrier();
        rd = rd + 1; if (rd >= 3) rd -= 3;
        bufB ^= 1;
    }
    // tail body b = NK-1 (odd): cur = bv1, nothing left to prefetch
    compute(&sA[rd][0], &sB[bufB][0]);
    writeB(&sB[bufB ^ 1][0], bv1);
    asm volatile("s_waitcnt vmcnt(0) lgkmcnt(0)" ::: "memory");
    __builtin_amdgcn_s_barrier();
    rd = rd + 1; if (rd >= 3) rd -= 3;
    bufB ^= 1;
    compute(&sA[rd][0], &sB[bufB][0]);   // chunk NK-1

    // ---- epilogue: SwiGLU via shfl_xor(1), store h bf16 ----
    #pragma unroll
    for (int rt = 0; rt < 4; ++rt) {
        #pragma unroll
        for (int reg = 0; reg < 4; ++reg) {
            int rl = wr * 64 + rt * 16 + quad * 4 + reg;
            bool ok = rl < rows;
            size_t grow = (size_t)(row0 + rl);
            #pragma unroll
            for (int ct = 0; ct < 4; ++ct) {
                float own = acc[rt][ct][reg];
                float oth = __shfl_xor(own, 1, 64);
                float g = (l16 & 1) ? oth : own;
                float u = (l16 & 1) ? own : oth;
                float sv = g / (1.f + __expf(-g)) * u;
                if (ok && !(l16 & 1)) {
                    int c = jb * 64 + ((wc * 64 + ct * 16 + l16) >> 1);
                    h[grow * INTER + c] = f2bf(sv);
                }
            }
        }
    }
}

// ---------------- GEMM2: out = h @ w2 ----------------
// Same pipelined structure; NK = 22.
__global__ __launch_bounds__(256, 3)
void gemm2(const unsigned short* __restrict__ h, const int* __restrict__ tpe,
           const float* __restrict__ w2, float* __restrict__ out)
{
    __shared__ int s_tpe[NEXP];
    __shared__ __align__(16) unsigned short sA[3][128 * 32];
    __shared__ __align__(16) unsigned short sB[2][128 * 32];

    int t = threadIdx.x;
    if (t < NEXP) s_tpe[t] = tpe[t];
    __syncthreads();

    int row0, rows, e;
    if (!map_tile(s_tpe, blockIdx.x, row0, rows, e)) return;
    int nb = blockIdx.y;   // 0..7

    int wv = t >> 6, lane = t & 63, l16 = lane & 15, quad = lane >> 4;
    int wr = wv >> 1, wc = wv & 1;
    int srow = lane >> 2, sblk = lane & 3;
    int gblk = sblk ^ (srow & 3);
    int bg = t & 15, kq = t >> 4;   // 16 col-groups x 8 cols, kq 0..15 -> 2 rows
    int xk = l16 & 3;

    const unsigned short* abase = h + (size_t)row0 * INTER;
    const float* bbase = w2 + (size_t)e * INTER * HIDDEN + nb * 128 + bg * 8;

    f32x4 acc[4][4];
    #pragma unroll
    for (int i = 0; i < 4; i++)
        #pragma unroll
        for (int j = 0; j < 4; j++) acc[i][j] = (f32x4)(0.f);

    auto loadB = [&](int ko, float4 (&bv)[4]) {
        const float* p = bbase + (size_t)(ko + 2 * kq) * HIDDEN;
        bv[0] = *(const float4*)(p);
        bv[1] = *(const float4*)(p + 4);
        bv[2] = *(const float4*)(p + HIDDEN);
        bv[3] = *(const float4*)(p + HIDDEN + 4);
    };
    auto stageA = [&](unsigned short* dst, int ko) {
        #pragma unroll
        for (int i = 0; i < 2; ++i) {
            int r = wv * 32 + i * 16 + srow;
            if (r < rows)
                load_lds16(abase + (size_t)r * INTER + ko + gblk * 8,
                           dst + (wv * 32 + i * 16) * 32);
        }
    };
    auto writeB = [&](unsigned short* dst, const float4 (&bv)[4]) {
        #pragma unroll
        for (int j = 0; j < 8; ++j) {
            float lo = (j < 4) ? fcomp(bv[0], j) : fcomp(bv[1], j - 4);
            float hi = (j < 4) ? fcomp(bv[2], j) : fcomp(bv[3], j - 4);
            int c = 8 * bg + j;
            int key = (c >> 3) & 3;
            int idx = c * 32 + (((kq >> 2) ^ key) << 3) + ((kq & 3) << 1);
            *(unsigned*)&dst[idx] = pkbf(lo, hi);
        }
    };
    auto compute = [&](const unsigned short* A, const unsigned short* B) {
        bf16x8 a[4], b[4];
        #pragma unroll
        for (int i = 0; i < 4; ++i) {
            a[i] = *(const bf16x8*)&A[(wr * 64 + i * 16 + l16) * 32 + ((quad ^ xk) << 3)];
            int c = wc * 64 + i * 16 + l16;
            b[i] = *(const bf16x8*)&B[c * 32 + ((quad ^ ((c >> 3) & 3)) << 3)];
        }
        #pragma unroll
        for (int rt = 0; rt < 4; ++rt)
            #pragma unroll
            for (int ct = 0; ct < 4; ++ct)
                acc[rt][ct] = __builtin_amdgcn_mfma_f32_16x16x32_bf16(a[rt], b[ct], acc[rt][ct], 0, 0, 0);
    };

    const int NK = INTER / 32;   // 22 chunks
    float4 bv0[4], bv1[4];

    stageA(&sA[0][0], 0);
    asm volatile("" ::: "memory");
    loadB(0, bv0);
    asm volatile("" ::: "memory");
    stageA(&sA[1][0], 32);
    asm volatile("" ::: "memory");
    loadB(32, bv1);
    writeB(&sB[0][0], bv0);
    asm volatile("s_waitcnt vmcnt(6) lgkmcnt(0)" ::: "memory");
    __builtin_amdgcn_s_barrier();

    int rd = 0, bufB = 0;
    for (int b = 1; b <= NK - 2; b += 2) {   // NK-2 = 20, even
        int st = rd + 2; if (st >= 3) st -= 3;
        stageA(&sA[st][0], (b + 1) * 32);
        asm volatile("" ::: "memory");
        loadB((b + 1) * 32, bv0);
        compute(&sA[rd][0], &sB[bufB][0]);
        writeB(&sB[bufB ^ 1][0], bv1);
        asm volatile("s_waitcnt vmcnt(6) lgkmcnt(0)" ::: "memory");
        __builtin_amdgcn_s_barrier();
        rd = rd + 1; if (rd >= 3) rd -= 3;
        bufB ^= 1;

        st = rd + 2; if (st >= 3) st -= 3;
        stageA(&sA[st][0], (b + 2) * 32);
        asm volatile("" ::: "memory");
        loadB((b + 2) * 32, bv1);
        compute(&sA[rd][0], &sB[bufB][0]);
        writeB(&sB[bufB ^ 1][0], bv0);
        asm volatile("s_waitcnt vmcnt(6) lgkmcnt(0)" ::: "memory");
        __builtin_amdgcn_s_barrier();
        rd = rd + 1; if (rd >= 3) rd -= 3;
        bufB ^= 1;
    }
    compute(&sA[rd][0], &sB[bufB][0]);
    writeB(&sB[bufB ^ 1][0], bv1);
    asm volatile("s_waitcnt vmcnt(0) lgkmcnt(0)" ::: "memory");
    __builtin_amdgcn_s_barrier();
    rd = rd + 1; if (rd >= 3) rd -= 3;
    bufB ^= 1;
    compute(&sA[rd][0], &sB[bufB][0]);

    #pragma unroll
    for (int rt = 0; rt < 4; ++rt) {
        #pragma unroll
        for (int reg = 0; reg < 4; ++reg) {
            int rl = wr * 64 + rt * 16 + quad * 4 + reg;
            if (rl < rows) {
                size_t grow = (size_t)(row0 + rl);
                #pragma unroll
                for (int ct = 0; ct < 4; ++ct)
                    out[grow * HIDDEN + nb * 128 + wc * 64 + ct * 16 + l16] = acc[rt][ct][reg];
            }
        }
    }
}

extern "C" void kernel_launch(void* const* d_in, const int* in_sizes, int n_in,
                              void* d_out, int out_size, void* d_ws, size_t ws_size,
                              hipStream_t stream) {
    const float* x    = (const float*)d_in[0];
    const int*   tpe  = (const int*)d_in[1];
    const float* w1w3 = (const float*)d_in[2];
    const float* w2   = (const float*)d_in[3];
    float* out = (float*)d_out;

    // ws (bf16 elems): h [8192*704] | xb [8192*1024]  (~27.5 MB)
    unsigned short* h  = (unsigned short*)d_ws;
    unsigned short* xb = h + (size_t)8192 * INTER;

    hipLaunchKernelGGL(cvt_x, dim3(1024), dim3(256), 0, stream, x, xb, 8192 * HIDDEN / 4);
    hipLaunchKernelGGL(gemm1_swiglu, dim3(96, 11), dim3(256), 0, stream, xb, tpe, w1w3, h);
    hipLaunchKernelGGL(gemm2, dim3(96, 8), dim3(256), 0, stream, h, tpe, w2, out);
}